// Round 1
// baseline (267.517 us; speedup 1.0000x reference)
//
#include <hip/hip_runtime.h>
#include <math.h>

// Problem constants (reference: x_l [16, 1, 1536, 1536] fp32, PATCH=3, ALPHA=1)
#define IMG_W 1536
#define IMG_H 1536
#define NIMG  16

// out(h,w) = sum_k v_k * exp(-v_k) / sum_k exp(-v_k), k over 3x3 zero-padded
// neighborhood. (The reference's "- x^2" shift is constant over the patch dim
// and cancels in softmax.) Zero-padded taps contribute v=0 -> e=1, v*e=0,
// so we just substitute v=0 for out-of-range taps and compute uniformly.
//
// Each thread: 4 contiguous output pixels. Loads 3 rows x 6 floats
// (aligned float4 + 2 guarded scalar halo loads per row). One exp per input
// element (18/thread = 4.5/pixel) shared across pixels via column sums.
__global__ __launch_bounds__(128)
void WeightedAverage_55551107006568_kernel(const float* __restrict__ x,
                                           float* __restrict__ out) {
    const int wg = blockIdx.x * 128 + threadIdx.x;   // 0..383 (group of 4 px)
    const int w0 = wg << 2;                          // first pixel column
    const int h  = blockIdx.y;
    const int n  = blockIdx.z;
    const size_t plane = (size_t)n * ((size_t)IMG_H * IMG_W);

    float v[3][6];
#pragma unroll
    for (int dr = 0; dr < 3; ++dr) {
        const int r = h + dr - 1;
        const bool rok = (r >= 0) && (r < IMG_H);
        const int rc = rok ? r : 0;                  // clamp ptr; loads guarded
        const float* rp = x + plane + (size_t)rc * IMG_W;
        float4 m = make_float4(0.f, 0.f, 0.f, 0.f);
        if (rok) m = *(const float4*)(rp + w0);
        float lft = 0.f, rgt = 0.f;
        if (rok && w0 > 0)           lft = rp[w0 - 1];
        if (rok && (w0 + 4) < IMG_W) rgt = rp[w0 + 4];
        v[dr][0] = lft;
        v[dr][1] = m.x; v[dr][2] = m.y; v[dr][3] = m.z; v[dr][4] = m.w;
        v[dr][5] = rgt;
    }

    // Column sums over the 3 rows of e = exp(-v) and ve = v * e
    float colE[6], colVE[6];
#pragma unroll
    for (int c = 0; c < 6; ++c) {
        const float e0 = __expf(-v[0][c]);
        const float e1 = __expf(-v[1][c]);
        const float e2 = __expf(-v[2][c]);
        colE[c]  = e0 + e1 + e2;
        colVE[c] = v[0][c] * e0 + v[1][c] * e1 + v[2][c] * e2;
    }

    float4 o;
    float* op = &o.x;
#pragma unroll
    for (int p = 0; p < 4; ++p) {
        const float den = colE[p] + colE[p + 1] + colE[p + 2];
        const float num = colVE[p] + colVE[p + 1] + colVE[p + 2];
        op[p] = num / den;
    }
    *(float4*)(out + plane + (size_t)h * IMG_W + w0) = o;
}

extern "C" void kernel_launch(void* const* d_in, const int* in_sizes, int n_in,
                              void* d_out, int out_size, void* d_ws, size_t ws_size,
                              hipStream_t stream) {
    const float* x = (const float*)d_in[0];
    float* out = (float*)d_out;
    dim3 grid(IMG_W / (128 * 4), IMG_H, NIMG);   // (3, 1536, 16)
    dim3 block(128, 1, 1);
    WeightedAverage_55551107006568_kernel<<<grid, block, 0, stream>>>(x, out);
}